// Round 5
// baseline (380.156 us; speedup 1.0000x reference)
//
#include <hip/hip_runtime.h>
#include <stdint.h>

static constexpr int THREADS = 256;
static constexpr int SCAN_THREADS = 1024;
static constexpr int CM  = 16384;          // rows per chunk
static constexpr int CN  = 16384;          // cols per chunk
static constexpr int CSZ = CM + CN;        // 32768 floats = 128 KB LDS
static constexpr int REP_T = 32;           // slices (templated fast path)
static constexpr int MAX_REP = 32;

typedef int   vint4   __attribute__((ext_vector_type(4)));
typedef float vfloat4 __attribute__((ext_vector_type(4)));

// ---------------------------------------------------------------------------
// init: zero fp64 accumulators + output scalar.
// ---------------------------------------------------------------------------
__global__ void kkt_init(double* __restrict__ acc, float* __restrict__ out) {
  int t = threadIdx.x;
  if (t < 4) acc[t] = 0.0;
  if (t == 0) out[0] = 0.0f;
}

// ---------------------------------------------------------------------------
// Scan (templated REP, unrolled): block (p = chunk, r = edge slice).
// Phase-split inner loop: 12 edge vec4-loads -> 16 predicated gathers ->
// 16 LDS atomic adds. ~16 independent memory chains per wave-iter to hide
// L3 edge latency + L2 gather latency at 4 waves/SIMD.
// ---------------------------------------------------------------------------
template <int REP>
__global__ __launch_bounds__(SCAN_THREADS) void kkt_scan_t(
    const int* __restrict__ rows, const int* __restrict__ cols,
    const float* __restrict__ attr,
    const float* __restrict__ x, const float* __restrict__ lam,
    float* __restrict__ partial, int E) {
  __shared__ float lds[CSZ];
  const int p = blockIdx.x / REP;
  const int r = blockIdx.x % REP;
  const unsigned baseM = (unsigned)(p * CM);
  const unsigned baseN = (unsigned)(p * CN);

  vfloat4* l4 = (vfloat4*)lds;
  for (int i = threadIdx.x; i < CSZ / 4; i += SCAN_THREADS) l4[i] = (vfloat4)(0.0f);
  __syncthreads();

  long per = (((long)E + REP - 1) / REP + 3) & ~3L;
  long e0 = per * r;  if (e0 > E) e0 = E;
  long e1 = e0 + per; if (e1 > E) e1 = E;
  long n4 = (e1 - e0) >> 2;

  const vint4*   rows4 = (const vint4*)(rows + e0);
  const vint4*   cols4 = (const vint4*)(cols + e0);
  const vfloat4* attr4 = (const vfloat4*)(attr + e0);
  const int tid = threadIdx.x;

  for (long qb = 0; qb < n4; qb += 4 * SCAN_THREADS) {
    vint4   rr[4], cc[4];
    vfloat4 aa[4];
    bool    gv[4];
    // phase 0: issue all edge loads
#pragma unroll
    for (int g = 0; g < 4; ++g) {
      long q = qb + (long)g * SCAN_THREADS + tid;
      gv[g] = q < n4;
      if (gv[g]) {
        rr[g] = __builtin_nontemporal_load(rows4 + q);
        cc[g] = __builtin_nontemporal_load(cols4 + q);
        aa[g] = __builtin_nontemporal_load(attr4 + q);
      } else {
        rr[g] = (vint4)(0); cc[g] = (vint4)(0); aa[g] = (vfloat4)(0.0f);
      }
    }
    // phases 1+2 per half (8 edges): filter + predicated gathers, then
    // LDS atomics. Half-split keeps VGPR under the 128 cap @1024thr.
#pragma unroll
    for (int h = 0; h < 2; ++h) {
      unsigned im[8], in_[8];
      bool     bm[8], bn[8];
      float    gx[8], gl[8];
      float    av[8];
#pragma unroll
      for (int e = 0; e < 8; ++e) {
        int g = h * 2 + (e >> 2);
        int j = e & 3;
        int rv = j == 0 ? rr[g].x : j == 1 ? rr[g].y : j == 2 ? rr[g].z : rr[g].w;
        int cv = j == 0 ? cc[g].x : j == 1 ? cc[g].y : j == 2 ? cc[g].z : cc[g].w;
        av[e]  = j == 0 ? aa[g].x : j == 1 ? aa[g].y : j == 2 ? aa[g].z : aa[g].w;
        im[e] = (unsigned)rv - baseM;
        in_[e] = (unsigned)cv - baseN;
        bm[e] = gv[g] && (im[e] < (unsigned)CM);
        bn[e] = gv[g] && (in_[e] < (unsigned)CN);
        gx[e] = bm[e] ? x[cv]  : 0.0f;
        gl[e] = bn[e] ? lam[rv] : 0.0f;
      }
#pragma unroll
      for (int e = 0; e < 8; ++e) {
        if (bm[e]) unsafeAtomicAdd(&lds[im[e]],       av[e] * gx[e]);
        if (bn[e]) unsafeAtomicAdd(&lds[CM + in_[e]], av[e] * gl[e]);
      }
    }
  }
  // scalar tail (E % 4 != 0, last slice only)
  for (long i = e0 + (n4 << 2) + tid; i < e1; i += SCAN_THREADS) {
    int rv = rows[i], cv = cols[i];
    float a = attr[i];
    unsigned mm = (unsigned)rv - baseM;
    if (mm < (unsigned)CM) unsafeAtomicAdd(&lds[mm], a * x[cv]);
    unsigned nn = (unsigned)cv - baseN;
    if (nn < (unsigned)CN) unsafeAtomicAdd(&lds[CM + nn], a * lam[rv]);
  }

  __syncthreads();
  vfloat4* d4 = (vfloat4*)(partial + (size_t)(p * REP + r) * CSZ);
  for (int i = threadIdx.x; i < CSZ / 4; i += SCAN_THREADS) d4[i] = l4[i];
}

// ---------------------------------------------------------------------------
// Loss (templated REP, unrolled replica sum). One thread per output element
// across m-side and n-side jointly; 32 independent strided loads pipeline.
// seg_mean_sq(v).sum() == sum(v*v)/per under uniform segment sizes.
// ---------------------------------------------------------------------------
template <int REP>
__global__ __launch_bounds__(THREADS) void kkt_loss_t(
    const float* __restrict__ partial,
    const float* __restrict__ bcat, const float* __restrict__ ccat,
    const float* __restrict__ lam, double* __restrict__ acc,
    int sum_m, int sum_n) {
  long idx = (long)blockIdx.x * THREADS + threadIdx.x;
  long stride = (long)gridDim.x * THREADS;
  long total = (long)sum_m + sum_n;
  double pr = 0.0, du = 0.0, st = 0.0, cs = 0.0;
  for (long i = idx; i < total; i += stride) {
    if (i < sum_m) {
      int ii = (int)i;
      int p = ii / CM, j = ii % CM;
      const float* b = partial + (size_t)(p * REP) * CSZ + j;
      float ax = 0.0f;
#pragma unroll
      for (int s = 0; s < REP; ++s) ax += b[(size_t)s * CSZ];
      float d  = ax - bcat[ii];
      float li = lam[ii];
      float pp   = d > 0.0f ? d : 0.0f;
      float u    = li < 0.0f ? -li : 0.0f;
      float comp = li * d;
      pr += (double)pp * pp;
      du += (double)u * u;
      cs += (double)comp * comp;
    } else {
      int ii = (int)(i - sum_m);
      int p = ii / CN, j = ii % CN;
      const float* b = partial + (size_t)(p * REP) * CSZ + CM + j;
      float at = 0.0f;
#pragma unroll
      for (int s = 0; s < REP; ++s) at += b[(size_t)s * CSZ];
      float sv = at + ccat[ii];
      st += (double)sv * sv;
    }
  }
  for (int off = 32; off > 0; off >>= 1) {
    pr += __shfl_down(pr, off);
    du += __shfl_down(du, off);
    st += __shfl_down(st, off);
    cs += __shfl_down(cs, off);
  }
  if ((threadIdx.x & 63) == 0) {
    unsafeAtomicAdd(&acc[0], pr);
    unsafeAtomicAdd(&acc[1], du);
    unsafeAtomicAdd(&acc[2], st);
    unsafeAtomicAdd(&acc[3], cs);
  }
}

// ---------------------------------------------------------------------------
// Dynamic-REP fallback (R3, proven 252 µs) for unexpected ws sizes.
// ---------------------------------------------------------------------------
__global__ __launch_bounds__(SCAN_THREADS) void kkt_scan_dyn(
    const int* __restrict__ rows, const int* __restrict__ cols,
    const float* __restrict__ attr,
    const float* __restrict__ x, const float* __restrict__ lam,
    float* __restrict__ partial, int E, int REP) {
  __shared__ float lds[CSZ];
  const int p = blockIdx.x / REP;
  const int r = blockIdx.x % REP;
  const int baseM = p * CM;
  const int baseN = p * CN;
  vfloat4* l4 = (vfloat4*)lds;
  for (int i = threadIdx.x; i < CSZ / 4; i += SCAN_THREADS) l4[i] = (vfloat4)(0.0f);
  __syncthreads();
  long per = (((long)E + REP - 1) / REP + 3) & ~3L;
  long e0 = per * r;  if (e0 > E) e0 = E;
  long e1 = e0 + per; if (e1 > E) e1 = E;
  int  n4 = (int)((e1 - e0) >> 2);
  const vint4*   rows4 = (const vint4*)(rows + e0);
  const vint4*   cols4 = (const vint4*)(cols + e0);
  const vfloat4* attr4 = (const vfloat4*)(attr + e0);
#define EDGE_ACC(RR, CC, AA)                                                 \
  do {                                                                       \
    unsigned mm = (unsigned)((RR) - baseM);                                  \
    if (mm < (unsigned)CM) unsafeAtomicAdd(&lds[mm], (AA) * x[(CC)]);        \
    unsigned nn = (unsigned)((CC) - baseN);                                  \
    if (nn < (unsigned)CN) unsafeAtomicAdd(&lds[CM + nn], (AA) * lam[(RR)]); \
  } while (0)
  for (int i = threadIdx.x; i < n4; i += SCAN_THREADS) {
    vint4 rr = rows4[i]; vint4 cc = cols4[i]; vfloat4 aa = attr4[i];
    EDGE_ACC(rr.x, cc.x, aa.x);
    EDGE_ACC(rr.y, cc.y, aa.y);
    EDGE_ACC(rr.z, cc.z, aa.z);
    EDGE_ACC(rr.w, cc.w, aa.w);
  }
  for (long i = e0 + ((long)n4 << 2) + threadIdx.x; i < e1; i += SCAN_THREADS) {
    int rr = rows[i], cc = cols[i];
    float aa = attr[i];
    EDGE_ACC(rr, cc, aa);
  }
#undef EDGE_ACC
  __syncthreads();
  vfloat4* d4 = (vfloat4*)(partial + (size_t)(p * REP + r) * CSZ);
  for (int i = threadIdx.x; i < CSZ / 4; i += SCAN_THREADS) d4[i] = l4[i];
}

__global__ __launch_bounds__(THREADS) void kkt_loss_dyn(
    const float* __restrict__ partial,
    const float* __restrict__ bcat, const float* __restrict__ ccat,
    const float* __restrict__ lam, double* __restrict__ acc,
    int sum_m, int sum_n, int REP) {
  int idx = blockIdx.x * blockDim.x + threadIdx.x;
  int stride = gridDim.x * blockDim.x;
  double pr = 0.0, du = 0.0, st = 0.0, cs = 0.0;
  for (int i = idx; i < sum_m; i += stride) {
    int p = i / CM, j = i - p * CM;
    const float* base = partial + (size_t)(p * REP) * CSZ + j;
    float ax = 0.0f;
    for (int rr = 0; rr < REP; ++rr) ax += base[(size_t)rr * CSZ];
    float d  = ax - bcat[i];
    float li = lam[i];
    float pp   = d > 0.0f ? d : 0.0f;
    float u    = li < 0.0f ? -li : 0.0f;
    float comp = li * d;
    pr += (double)pp * pp;
    du += (double)u * u;
    cs += (double)comp * comp;
  }
  for (int i = idx; i < sum_n; i += stride) {
    int p = i / CN, j = i - p * CN;
    const float* base = partial + (size_t)(p * REP) * CSZ + CM + j;
    float at = 0.0f;
    for (int rr = 0; rr < REP; ++rr) at += base[(size_t)rr * CSZ];
    float s = at + ccat[i];
    st += (double)s * s;
  }
  for (int off = 32; off > 0; off >>= 1) {
    pr += __shfl_down(pr, off);
    du += __shfl_down(du, off);
    st += __shfl_down(st, off);
    cs += __shfl_down(cs, off);
  }
  if ((threadIdx.x & 63) == 0) {
    unsafeAtomicAdd(&acc[0], pr);
    unsafeAtomicAdd(&acc[1], du);
    unsafeAtomicAdd(&acc[2], st);
    unsafeAtomicAdd(&acc[3], cs);
  }
}

// ---------------------------------------------------------------------------
// finalize
// ---------------------------------------------------------------------------
__global__ void kkt_finalize(const double* __restrict__ acc,
                             const int* __restrict__ Bp,
                             const int* __restrict__ mp,
                             const int* __restrict__ np_,
                             float* __restrict__ out) {
  double m = (double)mp[0];
  double n = (double)np_[0];
  double B = (double)Bp[0];
  double total =
      (0.1 * (acc[0] + acc[1]) / m + 0.6 * acc[2] / n + 0.2 * acc[3] / m) / B;
  out[0] = (float)total;
}

extern "C" void kernel_launch(void* const* d_in, const int* in_sizes, int n_in,
                              void* d_out, int out_size, void* d_ws, size_t ws_size,
                              hipStream_t stream) {
  const float* x    = (const float*)d_in[0];
  const float* lam  = (const float*)d_in[1];
  const int*   rows = (const int*)d_in[2];
  const int*   cols = (const int*)d_in[3];
  const float* attr = (const float*)d_in[4];
  const float* bcat = (const float*)d_in[5];
  const float* ccat = (const float*)d_in[6];
  const int*   Bp   = (const int*)d_in[7];
  const int*   mp   = (const int*)d_in[8];
  const int*   np_  = (const int*)d_in[9];

  const int sum_n = in_sizes[0];
  const int sum_m = in_sizes[1];
  const int E     = in_sizes[2];

  char*   ws  = (char*)d_ws;
  double* acc = (double*)ws;
  float*  buf = (float*)(ws + 64);
  float*  out = (float*)d_out;

  const int NPm = (sum_m + CM - 1) / CM;
  const int NPn = (sum_n + CN - 1) / CN;
  const int NP  = NPm > NPn ? NPm : NPn;

  size_t avail = ws_size > 64 ? ws_size - 64 : 0;
  const size_t need_t = (size_t)NP * REP_T * CSZ * sizeof(float);

  kkt_init<<<1, 64, 0, stream>>>(acc, out);

  if (avail >= need_t) {
    // fast templated path: REP=32, phase-split unrolled scan
    kkt_scan_t<REP_T><<<NP * REP_T, SCAN_THREADS, 0, stream>>>(
        rows, cols, attr, x, lam, buf, E);
    long total = (long)sum_m + sum_n;
    int lb = (int)((total + THREADS - 1) / THREADS);
    kkt_loss_t<REP_T><<<lb, THREADS, 0, stream>>>(buf, bcat, ccat, lam, acc,
                                                  sum_m, sum_n);
  } else {
    int REP = (int)(avail / ((size_t)NP * CSZ * sizeof(float)));
    if (REP > MAX_REP) REP = MAX_REP;
    if (REP < 1) REP = 1;
    kkt_scan_dyn<<<NP * REP, SCAN_THREADS, 0, stream>>>(rows, cols, attr, x,
                                                        lam, buf, E, REP);
    int lw = sum_m > sum_n ? sum_m : sum_n;
    int lb = (lw + THREADS - 1) / THREADS;
    if (lb > 1024) lb = 1024;
    kkt_loss_dyn<<<lb, THREADS, 0, stream>>>(buf, bcat, ccat, lam, acc,
                                             sum_m, sum_n, REP);
  }
  kkt_finalize<<<1, 1, 0, stream>>>(acc, Bp, mp, np_, out);
}

// Round 6
// 242.191 us; speedup vs baseline: 1.5697x; 1.5697x over previous
//
#include <hip/hip_runtime.h>
#include <stdint.h>

static constexpr int THREADS = 256;
static constexpr int SCAN_THREADS = 1024;
static constexpr int LOSS_BLOCKS = 512;
static constexpr int CM  = 16384;          // rows per chunk
static constexpr int CN  = 16384;          // cols per chunk
static constexpr int CSZ = CM + CN;        // 32768 floats = 128 KB LDS
static constexpr int REP_T = 32;           // slices (templated fast path)
static constexpr int MAX_REP = 32;

typedef int   vint4   __attribute__((ext_vector_type(4)));
typedef float vfloat4 __attribute__((ext_vector_type(4)));

// ---------------------------------------------------------------------------
// Scan (templated REP): block (p = chunk, r = edge slice). Proven structure
// (R3/R5, ~170 µs). blockIdx = p*REP + r  =>  XCD = r % 8: all 8 chunk-readers
// of a slice land on one XCD, so its L2 dedups the redundant edge reads.
// ---------------------------------------------------------------------------
template <int REP>
__global__ __launch_bounds__(SCAN_THREADS) void kkt_scan_t(
    const int* __restrict__ rows, const int* __restrict__ cols,
    const float* __restrict__ attr,
    const float* __restrict__ x, const float* __restrict__ lam,
    float* __restrict__ partial, int E) {
  __shared__ float lds[CSZ];
  const int p = blockIdx.x / REP;
  const int r = blockIdx.x % REP;
  const unsigned baseM = (unsigned)(p * CM);
  const unsigned baseN = (unsigned)(p * CN);

  vfloat4* l4 = (vfloat4*)lds;
  for (int i = threadIdx.x; i < CSZ / 4; i += SCAN_THREADS) l4[i] = (vfloat4)(0.0f);
  __syncthreads();

  long per = (((long)E + REP - 1) / REP + 3) & ~3L;
  long e0 = per * r;  if (e0 > E) e0 = E;
  long e1 = e0 + per; if (e1 > E) e1 = E;
  long n4 = (e1 - e0) >> 2;

  const vint4*   rows4 = (const vint4*)(rows + e0);
  const vint4*   cols4 = (const vint4*)(cols + e0);
  const vfloat4* attr4 = (const vfloat4*)(attr + e0);
  const int tid = threadIdx.x;

  for (long q = tid; q < n4; q += SCAN_THREADS) {
    vint4   rr = __builtin_nontemporal_load(rows4 + q);
    vint4   cc = __builtin_nontemporal_load(cols4 + q);
    vfloat4 aa = __builtin_nontemporal_load(attr4 + q);
#define EDGE_ACC(RR, CC, AA)                                                 \
    do {                                                                     \
      unsigned mm = (unsigned)(RR) - baseM;                                  \
      if (mm < (unsigned)CM) unsafeAtomicAdd(&lds[mm], (AA) * x[(CC)]);      \
      unsigned nn = (unsigned)(CC) - baseN;                                  \
      if (nn < (unsigned)CN) unsafeAtomicAdd(&lds[CM + nn], (AA) * lam[(RR)]); \
    } while (0)
    EDGE_ACC(rr.x, cc.x, aa.x);
    EDGE_ACC(rr.y, cc.y, aa.y);
    EDGE_ACC(rr.z, cc.z, aa.z);
    EDGE_ACC(rr.w, cc.w, aa.w);
  }
  // scalar tail (E % 4 != 0, last slice only)
  for (long i = e0 + (n4 << 2) + tid; i < e1; i += SCAN_THREADS) {
    int rv = rows[i], cv = cols[i];
    float a = attr[i];
    EDGE_ACC(rv, cv, a);
  }
#undef EDGE_ACC

  __syncthreads();
  vfloat4* d4 = (vfloat4*)(partial + (size_t)(p * REP + r) * CSZ);
  for (int i = threadIdx.x; i < CSZ / 4; i += SCAN_THREADS) d4[i] = l4[i];
}

// ---------------------------------------------------------------------------
// Loss (templated REP): per-block hierarchical reduction, ONE non-atomic
// fp64x4 store per block. No global atomics (the R5 204 µs wall was 16K
// same-address fp64 atomics serializing at ~50 ns each).
// seg_mean_sq(v).sum() == sum(v*v)/per under uniform segment sizes.
// ---------------------------------------------------------------------------
template <int REP>
__global__ __launch_bounds__(THREADS) void kkt_loss_t(
    const float* __restrict__ partial,
    const float* __restrict__ bcat, const float* __restrict__ ccat,
    const float* __restrict__ lam, double* __restrict__ bacc,
    int sum_m, int sum_n) {
  long idx = (long)blockIdx.x * THREADS + threadIdx.x;
  long stride = (long)gridDim.x * THREADS;
  long total = (long)sum_m + sum_n;
  double pr = 0.0, du = 0.0, st = 0.0, cs = 0.0;
  for (long i = idx; i < total; i += stride) {
    if (i < sum_m) {
      int ii = (int)i;
      int p = ii / CM, j = ii % CM;
      const float* b = partial + (size_t)(p * REP) * CSZ + j;
      float ax = 0.0f;
#pragma unroll
      for (int s = 0; s < REP; ++s) ax += b[(size_t)s * CSZ];
      float d  = ax - bcat[ii];
      float li = lam[ii];
      float pp   = d > 0.0f ? d : 0.0f;
      float u    = li < 0.0f ? -li : 0.0f;
      float comp = li * d;
      pr += (double)pp * pp;
      du += (double)u * u;
      cs += (double)comp * comp;
    } else {
      int ii = (int)(i - sum_m);
      int p = ii / CN, j = ii % CN;
      const float* b = partial + (size_t)(p * REP) * CSZ + CM + j;
      float at = 0.0f;
#pragma unroll
      for (int s = 0; s < REP; ++s) at += b[(size_t)s * CSZ];
      float sv = at + ccat[ii];
      st += (double)sv * sv;
    }
  }
  // wave butterfly
  for (int off = 32; off > 0; off >>= 1) {
    pr += __shfl_down(pr, off);
    du += __shfl_down(du, off);
    st += __shfl_down(st, off);
    cs += __shfl_down(cs, off);
  }
  __shared__ double sred[THREADS / 64][4];
  const int wv = threadIdx.x >> 6;
  if ((threadIdx.x & 63) == 0) {
    sred[wv][0] = pr; sred[wv][1] = du; sred[wv][2] = st; sred[wv][3] = cs;
  }
  __syncthreads();
  if (threadIdx.x == 0) {
    double a0 = 0, a1 = 0, a2 = 0, a3 = 0;
#pragma unroll
    for (int w = 0; w < THREADS / 64; ++w) {
      a0 += sred[w][0]; a1 += sred[w][1]; a2 += sred[w][2]; a3 += sred[w][3];
    }
    bacc[(size_t)blockIdx.x * 4 + 0] = a0;
    bacc[(size_t)blockIdx.x * 4 + 1] = a1;
    bacc[(size_t)blockIdx.x * 4 + 2] = a2;
    bacc[(size_t)blockIdx.x * 4 + 3] = a3;
  }
}

// ---------------------------------------------------------------------------
// finalize (fast path): sum per-block partials, apply weights. 1 block.
// ---------------------------------------------------------------------------
__global__ __launch_bounds__(THREADS) void kkt_finalize_fast(
    const double* __restrict__ bacc, int nblk,
    const int* __restrict__ Bp, const int* __restrict__ mp,
    const int* __restrict__ np_, float* __restrict__ out) {
  double v0 = 0, v1 = 0, v2 = 0, v3 = 0;
  for (int i = threadIdx.x; i < nblk; i += THREADS) {
    v0 += bacc[(size_t)i * 4 + 0];
    v1 += bacc[(size_t)i * 4 + 1];
    v2 += bacc[(size_t)i * 4 + 2];
    v3 += bacc[(size_t)i * 4 + 3];
  }
  for (int off = 32; off > 0; off >>= 1) {
    v0 += __shfl_down(v0, off);
    v1 += __shfl_down(v1, off);
    v2 += __shfl_down(v2, off);
    v3 += __shfl_down(v3, off);
  }
  __shared__ double sred[THREADS / 64][4];
  const int wv = threadIdx.x >> 6;
  if ((threadIdx.x & 63) == 0) {
    sred[wv][0] = v0; sred[wv][1] = v1; sred[wv][2] = v2; sred[wv][3] = v3;
  }
  __syncthreads();
  if (threadIdx.x == 0) {
    double a0 = 0, a1 = 0, a2 = 0, a3 = 0;
#pragma unroll
    for (int w = 0; w < THREADS / 64; ++w) {
      a0 += sred[w][0]; a1 += sred[w][1]; a2 += sred[w][2]; a3 += sred[w][3];
    }
    double m = (double)mp[0];
    double n = (double)np_[0];
    double B = (double)Bp[0];
    out[0] = (float)((0.1 * (a0 + a1) / m + 0.6 * a2 / n + 0.2 * a3 / m) / B);
  }
}

// ---------------------------------------------------------------------------
// Dynamic-REP fallback (proven R3 path) for unexpected ws sizes.
// ---------------------------------------------------------------------------
__global__ void kkt_init(double* __restrict__ acc, float* __restrict__ out) {
  int t = threadIdx.x;
  if (t < 4) acc[t] = 0.0;
  if (t == 0) out[0] = 0.0f;
}

__global__ __launch_bounds__(SCAN_THREADS) void kkt_scan_dyn(
    const int* __restrict__ rows, const int* __restrict__ cols,
    const float* __restrict__ attr,
    const float* __restrict__ x, const float* __restrict__ lam,
    float* __restrict__ partial, int E, int REP) {
  __shared__ float lds[CSZ];
  const int p = blockIdx.x / REP;
  const int r = blockIdx.x % REP;
  const int baseM = p * CM;
  const int baseN = p * CN;
  vfloat4* l4 = (vfloat4*)lds;
  for (int i = threadIdx.x; i < CSZ / 4; i += SCAN_THREADS) l4[i] = (vfloat4)(0.0f);
  __syncthreads();
  long per = (((long)E + REP - 1) / REP + 3) & ~3L;
  long e0 = per * r;  if (e0 > E) e0 = E;
  long e1 = e0 + per; if (e1 > E) e1 = E;
  int  n4 = (int)((e1 - e0) >> 2);
  const vint4*   rows4 = (const vint4*)(rows + e0);
  const vint4*   cols4 = (const vint4*)(cols + e0);
  const vfloat4* attr4 = (const vfloat4*)(attr + e0);
#define EDGE_ACC(RR, CC, AA)                                                 \
  do {                                                                       \
    unsigned mm = (unsigned)((RR) - baseM);                                  \
    if (mm < (unsigned)CM) unsafeAtomicAdd(&lds[mm], (AA) * x[(CC)]);        \
    unsigned nn = (unsigned)((CC) - baseN);                                  \
    if (nn < (unsigned)CN) unsafeAtomicAdd(&lds[CM + nn], (AA) * lam[(RR)]); \
  } while (0)
  for (int i = threadIdx.x; i < n4; i += SCAN_THREADS) {
    vint4 rr = rows4[i]; vint4 cc = cols4[i]; vfloat4 aa = attr4[i];
    EDGE_ACC(rr.x, cc.x, aa.x);
    EDGE_ACC(rr.y, cc.y, aa.y);
    EDGE_ACC(rr.z, cc.z, aa.z);
    EDGE_ACC(rr.w, cc.w, aa.w);
  }
  for (long i = e0 + ((long)n4 << 2) + threadIdx.x; i < e1; i += SCAN_THREADS) {
    int rr = rows[i], cc = cols[i];
    float aa = attr[i];
    EDGE_ACC(rr, cc, aa);
  }
#undef EDGE_ACC
  __syncthreads();
  vfloat4* d4 = (vfloat4*)(partial + (size_t)(p * REP + r) * CSZ);
  for (int i = threadIdx.x; i < CSZ / 4; i += SCAN_THREADS) d4[i] = l4[i];
}

__global__ __launch_bounds__(THREADS) void kkt_loss_dyn(
    const float* __restrict__ partial,
    const float* __restrict__ bcat, const float* __restrict__ ccat,
    const float* __restrict__ lam, double* __restrict__ acc,
    int sum_m, int sum_n, int REP) {
  int idx = blockIdx.x * blockDim.x + threadIdx.x;
  int stride = gridDim.x * blockDim.x;
  double pr = 0.0, du = 0.0, st = 0.0, cs = 0.0;
  for (int i = idx; i < sum_m; i += stride) {
    int p = i / CM, j = i - p * CM;
    const float* base = partial + (size_t)(p * REP) * CSZ + j;
    float ax = 0.0f;
    for (int rr = 0; rr < REP; ++rr) ax += base[(size_t)rr * CSZ];
    float d  = ax - bcat[i];
    float li = lam[i];
    float pp   = d > 0.0f ? d : 0.0f;
    float u    = li < 0.0f ? -li : 0.0f;
    float comp = li * d;
    pr += (double)pp * pp;
    du += (double)u * u;
    cs += (double)comp * comp;
  }
  for (int i = idx; i < sum_n; i += stride) {
    int p = i / CN, j = i - p * CN;
    const float* base = partial + (size_t)(p * REP) * CSZ + CM + j;
    float at = 0.0f;
    for (int rr = 0; rr < REP; ++rr) at += base[(size_t)rr * CSZ];
    float s = at + ccat[i];
    st += (double)s * s;
  }
  for (int off = 32; off > 0; off >>= 1) {
    pr += __shfl_down(pr, off);
    du += __shfl_down(du, off);
    st += __shfl_down(st, off);
    cs += __shfl_down(cs, off);
  }
  if ((threadIdx.x & 63) == 0) {
    unsafeAtomicAdd(&acc[0], pr);
    unsafeAtomicAdd(&acc[1], du);
    unsafeAtomicAdd(&acc[2], st);
    unsafeAtomicAdd(&acc[3], cs);
  }
}

__global__ void kkt_finalize(const double* __restrict__ acc,
                             const int* __restrict__ Bp,
                             const int* __restrict__ mp,
                             const int* __restrict__ np_,
                             float* __restrict__ out) {
  double m = (double)mp[0];
  double n = (double)np_[0];
  double B = (double)Bp[0];
  double total =
      (0.1 * (acc[0] + acc[1]) / m + 0.6 * acc[2] / n + 0.2 * acc[3] / m) / B;
  out[0] = (float)total;
}

extern "C" void kernel_launch(void* const* d_in, const int* in_sizes, int n_in,
                              void* d_out, int out_size, void* d_ws, size_t ws_size,
                              hipStream_t stream) {
  const float* x    = (const float*)d_in[0];
  const float* lam  = (const float*)d_in[1];
  const int*   rows = (const int*)d_in[2];
  const int*   cols = (const int*)d_in[3];
  const float* attr = (const float*)d_in[4];
  const float* bcat = (const float*)d_in[5];
  const float* ccat = (const float*)d_in[6];
  const int*   Bp   = (const int*)d_in[7];
  const int*   mp   = (const int*)d_in[8];
  const int*   np_  = (const int*)d_in[9];

  const int sum_n = in_sizes[0];
  const int sum_m = in_sizes[1];
  const int E     = in_sizes[2];

  char*   ws   = (char*)d_ws;
  double* acc  = (double*)ws;                    // 32 B (fallback)
  double* bacc = (double*)(ws + 256);            // LOSS_BLOCKS*4 doubles
  float*  buf  = (float*)(ws + 256 + LOSS_BLOCKS * 4 * sizeof(double));
  float*  out  = (float*)d_out;

  const int NPm = (sum_m + CM - 1) / CM;
  const int NPn = (sum_n + CN - 1) / CN;
  const int NP  = NPm > NPn ? NPm : NPn;

  const size_t head = 256 + (size_t)LOSS_BLOCKS * 4 * sizeof(double);
  size_t avail = ws_size > head ? ws_size - head : 0;
  const size_t need_t = (size_t)NP * REP_T * CSZ * sizeof(float);

  if (avail >= need_t) {
    // fast path: templated scan + atomic-free hierarchical reduction
    kkt_scan_t<REP_T><<<NP * REP_T, SCAN_THREADS, 0, stream>>>(
        rows, cols, attr, x, lam, buf, E);
    kkt_loss_t<REP_T><<<LOSS_BLOCKS, THREADS, 0, stream>>>(
        buf, bcat, ccat, lam, bacc, sum_m, sum_n);
    kkt_finalize_fast<<<1, THREADS, 0, stream>>>(bacc, LOSS_BLOCKS, Bp, mp,
                                                 np_, out);
  } else {
    float* fbuf = (float*)(ws + 64);
    size_t favail = ws_size > 64 ? ws_size - 64 : 0;
    int REP = (int)(favail / ((size_t)NP * CSZ * sizeof(float)));
    if (REP > MAX_REP) REP = MAX_REP;
    if (REP < 1) REP = 1;
    kkt_init<<<1, 64, 0, stream>>>(acc, out);
    kkt_scan_dyn<<<NP * REP, SCAN_THREADS, 0, stream>>>(rows, cols, attr, x,
                                                        lam, fbuf, E, REP);
    int lw = sum_m > sum_n ? sum_m : sum_n;
    int lb = (lw + THREADS - 1) / THREADS;
    if (lb > 1024) lb = 1024;
    kkt_loss_dyn<<<lb, THREADS, 0, stream>>>(fbuf, bcat, ccat, lam, acc,
                                             sum_m, sum_n, REP);
    kkt_finalize<<<1, 1, 0, stream>>>(acc, Bp, mp, np_, out);
  }
}

// Round 7
// 136.093 us; speedup vs baseline: 2.7934x; 1.7796x over previous
//
#include <hip/hip_runtime.h>
#include <stdint.h>

static constexpr int THREADS = 256;
static constexpr int SCAN_THREADS = 1024;
static constexpr int LOSS_BLOCKS = 512;
static constexpr int CM  = 16384;          // rows per chunk
static constexpr int CN  = 16384;          // cols per chunk
static constexpr int CSZ = CM + CN;        // 32768 floats = 128 KB LDS
static constexpr int REP_T = 32;           // slices (templated fast path)
static constexpr int MAX_REP = 32;

typedef int   vint4   __attribute__((ext_vector_type(4)));
typedef float vfloat4 __attribute__((ext_vector_type(4)));

// ---------------------------------------------------------------------------
// Scan (templated REP): block (p = chunk, r = edge slice). Proven structure
// (R3, ~178 µs). blockIdx = p*REP + r => XCD = r % 8: all 8 chunk-readers of
// a slice land on one XCD, so its L2 dedups the redundant edge reads.
// Edge loads are PLAIN (cached) — R6 proved nontemporal here costs +46 µs
// (+12 MB HBM refetch) by defeating the L2/L3 reuse.
// Partial flush is nontemporal: written once, read once by the loss kernel;
// keeps the 33 MB stream from evicting L3-resident edges between replays.
// ---------------------------------------------------------------------------
template <int REP>
__global__ __launch_bounds__(SCAN_THREADS) void kkt_scan_t(
    const int* __restrict__ rows, const int* __restrict__ cols,
    const float* __restrict__ attr,
    const float* __restrict__ x, const float* __restrict__ lam,
    float* __restrict__ partial, int E) {
  __shared__ float lds[CSZ];
  const int p = blockIdx.x / REP;
  const int r = blockIdx.x % REP;
  const unsigned baseM = (unsigned)(p * CM);
  const unsigned baseN = (unsigned)(p * CN);

  vfloat4* l4 = (vfloat4*)lds;
  for (int i = threadIdx.x; i < CSZ / 4; i += SCAN_THREADS) l4[i] = (vfloat4)(0.0f);
  __syncthreads();

  long per = (((long)E + REP - 1) / REP + 3) & ~3L;
  long e0 = per * r;  if (e0 > E) e0 = E;
  long e1 = e0 + per; if (e1 > E) e1 = E;
  long n4 = (e1 - e0) >> 2;

  const vint4*   rows4 = (const vint4*)(rows + e0);
  const vint4*   cols4 = (const vint4*)(cols + e0);
  const vfloat4* attr4 = (const vfloat4*)(attr + e0);
  const int tid = threadIdx.x;

  for (long q = tid; q < n4; q += SCAN_THREADS) {
    vint4   rr = rows4[q];
    vint4   cc = cols4[q];
    vfloat4 aa = attr4[q];
#define EDGE_ACC(RR, CC, AA)                                                 \
    do {                                                                     \
      unsigned mm = (unsigned)(RR) - baseM;                                  \
      if (mm < (unsigned)CM) unsafeAtomicAdd(&lds[mm], (AA) * x[(CC)]);      \
      unsigned nn = (unsigned)(CC) - baseN;                                  \
      if (nn < (unsigned)CN) unsafeAtomicAdd(&lds[CM + nn], (AA) * lam[(RR)]); \
    } while (0)
    EDGE_ACC(rr.x, cc.x, aa.x);
    EDGE_ACC(rr.y, cc.y, aa.y);
    EDGE_ACC(rr.z, cc.z, aa.z);
    EDGE_ACC(rr.w, cc.w, aa.w);
  }
  // scalar tail (E % 4 != 0, last slice only)
  for (long i = e0 + (n4 << 2) + tid; i < e1; i += SCAN_THREADS) {
    int rv = rows[i], cv = cols[i];
    float a = attr[i];
    EDGE_ACC(rv, cv, a);
  }
#undef EDGE_ACC

  __syncthreads();
  vfloat4* d4 = (vfloat4*)(partial + (size_t)(p * REP + r) * CSZ);
  for (int i = threadIdx.x; i < CSZ / 4; i += SCAN_THREADS)
    __builtin_nontemporal_store(l4[i], d4 + i);
}

// ---------------------------------------------------------------------------
// Loss (templated REP): per-block hierarchical reduction, ONE non-atomic
// fp64x4 store per block (R5's 204 µs wall was same-address fp64 atomics).
// Partial reads nontemporal (single-use stream).
// seg_mean_sq(v).sum() == sum(v*v)/per under uniform segment sizes.
// ---------------------------------------------------------------------------
template <int REP>
__global__ __launch_bounds__(THREADS) void kkt_loss_t(
    const float* __restrict__ partial,
    const float* __restrict__ bcat, const float* __restrict__ ccat,
    const float* __restrict__ lam, double* __restrict__ bacc,
    int sum_m, int sum_n) {
  long idx = (long)blockIdx.x * THREADS + threadIdx.x;
  long stride = (long)gridDim.x * THREADS;
  long total = (long)sum_m + sum_n;
  double pr = 0.0, du = 0.0, st = 0.0, cs = 0.0;
  for (long i = idx; i < total; i += stride) {
    if (i < sum_m) {
      int ii = (int)i;
      int p = ii / CM, j = ii % CM;
      const float* b = partial + (size_t)(p * REP) * CSZ + j;
      float ax = 0.0f;
#pragma unroll
      for (int s = 0; s < REP; ++s)
        ax += __builtin_nontemporal_load(b + (size_t)s * CSZ);
      float d  = ax - bcat[ii];
      float li = lam[ii];
      float pp   = d > 0.0f ? d : 0.0f;
      float u    = li < 0.0f ? -li : 0.0f;
      float comp = li * d;
      pr += (double)pp * pp;
      du += (double)u * u;
      cs += (double)comp * comp;
    } else {
      int ii = (int)(i - sum_m);
      int p = ii / CN, j = ii % CN;
      const float* b = partial + (size_t)(p * REP) * CSZ + CM + j;
      float at = 0.0f;
#pragma unroll
      for (int s = 0; s < REP; ++s)
        at += __builtin_nontemporal_load(b + (size_t)s * CSZ);
      float sv = at + ccat[ii];
      st += (double)sv * sv;
    }
  }
  // wave butterfly
  for (int off = 32; off > 0; off >>= 1) {
    pr += __shfl_down(pr, off);
    du += __shfl_down(du, off);
    st += __shfl_down(st, off);
    cs += __shfl_down(cs, off);
  }
  __shared__ double sred[THREADS / 64][4];
  const int wv = threadIdx.x >> 6;
  if ((threadIdx.x & 63) == 0) {
    sred[wv][0] = pr; sred[wv][1] = du; sred[wv][2] = st; sred[wv][3] = cs;
  }
  __syncthreads();
  if (threadIdx.x == 0) {
    double a0 = 0, a1 = 0, a2 = 0, a3 = 0;
#pragma unroll
    for (int w = 0; w < THREADS / 64; ++w) {
      a0 += sred[w][0]; a1 += sred[w][1]; a2 += sred[w][2]; a3 += sred[w][3];
    }
    bacc[(size_t)blockIdx.x * 4 + 0] = a0;
    bacc[(size_t)blockIdx.x * 4 + 1] = a1;
    bacc[(size_t)blockIdx.x * 4 + 2] = a2;
    bacc[(size_t)blockIdx.x * 4 + 3] = a3;
  }
}

// ---------------------------------------------------------------------------
// finalize (fast path): sum per-block partials, apply weights. 1 block.
// ---------------------------------------------------------------------------
__global__ __launch_bounds__(THREADS) void kkt_finalize_fast(
    const double* __restrict__ bacc, int nblk,
    const int* __restrict__ Bp, const int* __restrict__ mp,
    const int* __restrict__ np_, float* __restrict__ out) {
  double v0 = 0, v1 = 0, v2 = 0, v3 = 0;
  for (int i = threadIdx.x; i < nblk; i += THREADS) {
    v0 += bacc[(size_t)i * 4 + 0];
    v1 += bacc[(size_t)i * 4 + 1];
    v2 += bacc[(size_t)i * 4 + 2];
    v3 += bacc[(size_t)i * 4 + 3];
  }
  for (int off = 32; off > 0; off >>= 1) {
    v0 += __shfl_down(v0, off);
    v1 += __shfl_down(v1, off);
    v2 += __shfl_down(v2, off);
    v3 += __shfl_down(v3, off);
  }
  __shared__ double sred[THREADS / 64][4];
  const int wv = threadIdx.x >> 6;
  if ((threadIdx.x & 63) == 0) {
    sred[wv][0] = v0; sred[wv][1] = v1; sred[wv][2] = v2; sred[wv][3] = v3;
  }
  __syncthreads();
  if (threadIdx.x == 0) {
    double a0 = 0, a1 = 0, a2 = 0, a3 = 0;
#pragma unroll
    for (int w = 0; w < THREADS / 64; ++w) {
      a0 += sred[w][0]; a1 += sred[w][1]; a2 += sred[w][2]; a3 += sred[w][3];
    }
    double m = (double)mp[0];
    double n = (double)np_[0];
    double B = (double)Bp[0];
    out[0] = (float)((0.1 * (a0 + a1) / m + 0.6 * a2 / n + 0.2 * a3 / m) / B);
  }
}

// ---------------------------------------------------------------------------
// Dynamic-REP fallback (proven R3 path) for unexpected ws sizes.
// ---------------------------------------------------------------------------
__global__ void kkt_init(double* __restrict__ acc, float* __restrict__ out) {
  int t = threadIdx.x;
  if (t < 4) acc[t] = 0.0;
  if (t == 0) out[0] = 0.0f;
}

__global__ __launch_bounds__(SCAN_THREADS) void kkt_scan_dyn(
    const int* __restrict__ rows, const int* __restrict__ cols,
    const float* __restrict__ attr,
    const float* __restrict__ x, const float* __restrict__ lam,
    float* __restrict__ partial, int E, int REP) {
  __shared__ float lds[CSZ];
  const int p = blockIdx.x / REP;
  const int r = blockIdx.x % REP;
  const int baseM = p * CM;
  const int baseN = p * CN;
  vfloat4* l4 = (vfloat4*)lds;
  for (int i = threadIdx.x; i < CSZ / 4; i += SCAN_THREADS) l4[i] = (vfloat4)(0.0f);
  __syncthreads();
  long per = (((long)E + REP - 1) / REP + 3) & ~3L;
  long e0 = per * r;  if (e0 > E) e0 = E;
  long e1 = e0 + per; if (e1 > E) e1 = E;
  int  n4 = (int)((e1 - e0) >> 2);
  const vint4*   rows4 = (const vint4*)(rows + e0);
  const vint4*   cols4 = (const vint4*)(cols + e0);
  const vfloat4* attr4 = (const vfloat4*)(attr + e0);
#define EDGE_ACC(RR, CC, AA)                                                 \
  do {                                                                       \
    unsigned mm = (unsigned)((RR) - baseM);                                  \
    if (mm < (unsigned)CM) unsafeAtomicAdd(&lds[mm], (AA) * x[(CC)]);        \
    unsigned nn = (unsigned)((CC) - baseN);                                  \
    if (nn < (unsigned)CN) unsafeAtomicAdd(&lds[CM + nn], (AA) * lam[(RR)]); \
  } while (0)
  for (int i = threadIdx.x; i < n4; i += SCAN_THREADS) {
    vint4 rr = rows4[i]; vint4 cc = cols4[i]; vfloat4 aa = attr4[i];
    EDGE_ACC(rr.x, cc.x, aa.x);
    EDGE_ACC(rr.y, cc.y, aa.y);
    EDGE_ACC(rr.z, cc.z, aa.z);
    EDGE_ACC(rr.w, cc.w, aa.w);
  }
  for (long i = e0 + ((long)n4 << 2) + threadIdx.x; i < e1; i += SCAN_THREADS) {
    int rr = rows[i], cc = cols[i];
    float aa = attr[i];
    EDGE_ACC(rr, cc, aa);
  }
#undef EDGE_ACC
  __syncthreads();
  vfloat4* d4 = (vfloat4*)(partial + (size_t)(p * REP + r) * CSZ);
  for (int i = threadIdx.x; i < CSZ / 4; i += SCAN_THREADS) d4[i] = l4[i];
}

__global__ __launch_bounds__(THREADS) void kkt_loss_dyn(
    const float* __restrict__ partial,
    const float* __restrict__ bcat, const float* __restrict__ ccat,
    const float* __restrict__ lam, double* __restrict__ acc,
    int sum_m, int sum_n, int REP) {
  int idx = blockIdx.x * blockDim.x + threadIdx.x;
  int stride = gridDim.x * blockDim.x;
  double pr = 0.0, du = 0.0, st = 0.0, cs = 0.0;
  for (int i = idx; i < sum_m; i += stride) {
    int p = i / CM, j = i - p * CM;
    const float* base = partial + (size_t)(p * REP) * CSZ + j;
    float ax = 0.0f;
    for (int rr = 0; rr < REP; ++rr) ax += base[(size_t)rr * CSZ];
    float d  = ax - bcat[i];
    float li = lam[i];
    float pp   = d > 0.0f ? d : 0.0f;
    float u    = li < 0.0f ? -li : 0.0f;
    float comp = li * d;
    pr += (double)pp * pp;
    du += (double)u * u;
    cs += (double)comp * comp;
  }
  for (int i = idx; i < sum_n; i += stride) {
    int p = i / CN, j = i - p * CN;
    const float* base = partial + (size_t)(p * REP) * CSZ + CM + j;
    float at = 0.0f;
    for (int rr = 0; rr < REP; ++rr) at += base[(size_t)rr * CSZ];
    float s = at + ccat[i];
    st += (double)s * s;
  }
  for (int off = 32; off > 0; off >>= 1) {
    pr += __shfl_down(pr, off);
    du += __shfl_down(du, off);
    st += __shfl_down(st, off);
    cs += __shfl_down(cs, off);
  }
  if ((threadIdx.x & 63) == 0) {
    unsafeAtomicAdd(&acc[0], pr);
    unsafeAtomicAdd(&acc[1], du);
    unsafeAtomicAdd(&acc[2], st);
    unsafeAtomicAdd(&acc[3], cs);
  }
}

__global__ void kkt_finalize(const double* __restrict__ acc,
                             const int* __restrict__ Bp,
                             const int* __restrict__ mp,
                             const int* __restrict__ np_,
                             float* __restrict__ out) {
  double m = (double)mp[0];
  double n = (double)np_[0];
  double B = (double)Bp[0];
  double total =
      (0.1 * (acc[0] + acc[1]) / m + 0.6 * acc[2] / n + 0.2 * acc[3] / m) / B;
  out[0] = (float)total;
}

extern "C" void kernel_launch(void* const* d_in, const int* in_sizes, int n_in,
                              void* d_out, int out_size, void* d_ws, size_t ws_size,
                              hipStream_t stream) {
  const float* x    = (const float*)d_in[0];
  const float* lam  = (const float*)d_in[1];
  const int*   rows = (const int*)d_in[2];
  const int*   cols = (const int*)d_in[3];
  const float* attr = (const float*)d_in[4];
  const float* bcat = (const float*)d_in[5];
  const float* ccat = (const float*)d_in[6];
  const int*   Bp   = (const int*)d_in[7];
  const int*   mp   = (const int*)d_in[8];
  const int*   np_  = (const int*)d_in[9];

  const int sum_n = in_sizes[0];
  const int sum_m = in_sizes[1];
  const int E     = in_sizes[2];

  char*   ws   = (char*)d_ws;
  double* acc  = (double*)ws;                    // 32 B (fallback)
  double* bacc = (double*)(ws + 256);            // LOSS_BLOCKS*4 doubles
  float*  buf  = (float*)(ws + 256 + LOSS_BLOCKS * 4 * sizeof(double));
  float*  out  = (float*)d_out;

  const int NPm = (sum_m + CM - 1) / CM;
  const int NPn = (sum_n + CN - 1) / CN;
  const int NP  = NPm > NPn ? NPm : NPn;

  const size_t head = 256 + (size_t)LOSS_BLOCKS * 4 * sizeof(double);
  size_t avail = ws_size > head ? ws_size - head : 0;
  const size_t need_t = (size_t)NP * REP_T * CSZ * sizeof(float);

  if (avail >= need_t) {
    // fast path: templated scan + atomic-free hierarchical reduction
    kkt_scan_t<REP_T><<<NP * REP_T, SCAN_THREADS, 0, stream>>>(
        rows, cols, attr, x, lam, buf, E);
    kkt_loss_t<REP_T><<<LOSS_BLOCKS, THREADS, 0, stream>>>(
        buf, bcat, ccat, lam, bacc, sum_m, sum_n);
    kkt_finalize_fast<<<1, THREADS, 0, stream>>>(bacc, LOSS_BLOCKS, Bp, mp,
                                                 np_, out);
  } else {
    float* fbuf = (float*)(ws + 64);
    size_t favail = ws_size > 64 ? ws_size - 64 : 0;
    int REP = (int)(favail / ((size_t)NP * CSZ * sizeof(float)));
    if (REP > MAX_REP) REP = MAX_REP;
    if (REP < 1) REP = 1;
    kkt_init<<<1, 64, 0, stream>>>(acc, out);
    kkt_scan_dyn<<<NP * REP, SCAN_THREADS, 0, stream>>>(rows, cols, attr, x,
                                                        lam, fbuf, E, REP);
    int lw = sum_m > sum_n ? sum_m : sum_n;
    int lb = (lw + THREADS - 1) / THREADS;
    if (lb > 1024) lb = 1024;
    kkt_loss_dyn<<<lb, THREADS, 0, stream>>>(fbuf, bcat, ccat, lam, acc,
                                             sum_m, sum_n, REP);
    kkt_finalize<<<1, 1, 0, stream>>>(acc, Bp, mp, np_, out);
  }
}

// Round 8
// 121.568 us; speedup vs baseline: 3.1271x; 1.1195x over previous
//
#include <hip/hip_runtime.h>
#include <stdint.h>

static constexpr int THREADS = 256;
static constexpr int SCAN_THREADS = 1024;
static constexpr int LOSS_BLOCKS = 512;
static constexpr int CHUNK = 32768;        // one-side chunk: 32768 fp32 = 128 KB LDS
static constexpr int REP_T = 32;           // edge slices (templated fast path)

// fallback (R3-family) constants
static constexpr int CM  = 16384;
static constexpr int CN  = 16384;
static constexpr int CSZ = CM + CN;
static constexpr int MAX_REP = 32;

typedef int   vint4   __attribute__((ext_vector_type(4)));
typedef float vfloat4 __attribute__((ext_vector_type(4)));

// ---------------------------------------------------------------------------
// Split scan (templated REP): block (q = side-chunk, r = edge slice).
// q < NPr: row-chunk [q*CHUNK, ..): accumulate a*x[c] by row.
// q >= NPr: col-chunk: accumulate a*lam[r] by col.
// vs R7's combined kernel: hit rate 1/8 -> 1/4, predicated gather+DS
// instruction count halves (VMEM addr pipe pays full cost per instr
// regardless of active lanes). Edge traffic unchanged; bid = q*REP + r
// keeps all 8 blocks of slice r on XCD r%8 so its L2 dedups edge reads.
// Edge loads PLAIN (8x reused; R6: NT here cost +46 µs). Flush NT
// (single-use stream).
// ---------------------------------------------------------------------------
template <int REP>
__global__ __launch_bounds__(SCAN_THREADS) void kkt_scan2_t(
    const int* __restrict__ rows, const int* __restrict__ cols,
    const float* __restrict__ attr,
    const float* __restrict__ x, const float* __restrict__ lam,
    float* __restrict__ partial, int E, int NPr) {
  __shared__ float lds[CHUNK];
  const int q = blockIdx.x / REP;
  const int r = blockIdx.x % REP;
  const bool rowside = q < NPr;
  const unsigned base = (unsigned)((rowside ? q : q - NPr) * CHUNK);

  vfloat4* l4 = (vfloat4*)lds;
  for (int i = threadIdx.x; i < CHUNK / 4; i += SCAN_THREADS) l4[i] = (vfloat4)(0.0f);
  __syncthreads();

  long per = (((long)E + REP - 1) / REP + 3) & ~3L;
  long e0 = per * r;  if (e0 > E) e0 = E;
  long e1 = e0 + per; if (e1 > E) e1 = E;
  long n4 = (e1 - e0) >> 2;

  const vint4*   rows4 = (const vint4*)(rows + e0);
  const vint4*   cols4 = (const vint4*)(cols + e0);
  const vfloat4* attr4 = (const vfloat4*)(attr + e0);
  const int tid = threadIdx.x;

  if (rowside) {
    for (long qq = tid; qq < n4; qq += SCAN_THREADS) {
      vint4   rr = rows4[qq];
      vint4   cc = cols4[qq];
      vfloat4 aa = attr4[qq];
#define ROW_ACC(RR, CC, AA)                                                  \
      do {                                                                   \
        unsigned k = (unsigned)(RR) - base;                                  \
        if (k < (unsigned)CHUNK) unsafeAtomicAdd(&lds[k], (AA) * x[(CC)]);   \
      } while (0)
      ROW_ACC(rr.x, cc.x, aa.x);
      ROW_ACC(rr.y, cc.y, aa.y);
      ROW_ACC(rr.z, cc.z, aa.z);
      ROW_ACC(rr.w, cc.w, aa.w);
    }
    for (long i = e0 + (n4 << 2) + tid; i < e1; i += SCAN_THREADS) {
      int rv = rows[i], cv = cols[i];
      float a = attr[i];
      ROW_ACC(rv, cv, a);
    }
#undef ROW_ACC
  } else {
    for (long qq = tid; qq < n4; qq += SCAN_THREADS) {
      vint4   rr = rows4[qq];
      vint4   cc = cols4[qq];
      vfloat4 aa = attr4[qq];
#define COL_ACC(RR, CC, AA)                                                  \
      do {                                                                   \
        unsigned k = (unsigned)(CC) - base;                                  \
        if (k < (unsigned)CHUNK) unsafeAtomicAdd(&lds[k], (AA) * lam[(RR)]); \
      } while (0)
      COL_ACC(rr.x, cc.x, aa.x);
      COL_ACC(rr.y, cc.y, aa.y);
      COL_ACC(rr.z, cc.z, aa.z);
      COL_ACC(rr.w, cc.w, aa.w);
    }
    for (long i = e0 + (n4 << 2) + tid; i < e1; i += SCAN_THREADS) {
      int rv = rows[i], cv = cols[i];
      float a = attr[i];
      COL_ACC(rv, cv, a);
    }
#undef COL_ACC
  }

  __syncthreads();
  vfloat4* d4 = (vfloat4*)(partial + (size_t)blockIdx.x * CHUNK);
  for (int i = threadIdx.x; i < CHUNK / 4; i += SCAN_THREADS)
    __builtin_nontemporal_store(l4[i], d4 + i);
}

// ---------------------------------------------------------------------------
// Loss (templated REP): sum REP replicas per element + loss math; per-block
// hierarchical reduction, ONE non-atomic fp64x4 store per block (same-address
// fp64 atomics were R5's 204 µs wall). Partial reads NT (single-use).
// seg_mean_sq(v).sum() == sum(v*v)/per under uniform segment sizes.
// Layout: row slabs [0, NPr*REP), col slabs [NPr*REP, ...), slab = CHUNK fp32.
// ---------------------------------------------------------------------------
template <int REP>
__global__ __launch_bounds__(THREADS) void kkt_loss2_t(
    const float* __restrict__ partial,
    const float* __restrict__ bcat, const float* __restrict__ ccat,
    const float* __restrict__ lam, double* __restrict__ bacc,
    int sum_m, int sum_n, int NPr) {
  long idx = (long)blockIdx.x * THREADS + threadIdx.x;
  long stride = (long)gridDim.x * THREADS;
  long total = (long)sum_m + sum_n;
  const size_t col_off = (size_t)NPr * REP * CHUNK;
  double pr = 0.0, du = 0.0, st = 0.0, cs = 0.0;
  for (long i = idx; i < total; i += stride) {
    if (i < sum_m) {
      int ii = (int)i;
      int p = ii / CHUNK, j = ii & (CHUNK - 1);
      const float* b = partial + (size_t)(p * REP) * CHUNK + j;
      float ax = 0.0f;
#pragma unroll
      for (int s = 0; s < REP; ++s)
        ax += __builtin_nontemporal_load(b + (size_t)s * CHUNK);
      float d  = ax - bcat[ii];
      float li = lam[ii];
      float pp   = d > 0.0f ? d : 0.0f;
      float u    = li < 0.0f ? -li : 0.0f;
      float comp = li * d;
      pr += (double)pp * pp;
      du += (double)u * u;
      cs += (double)comp * comp;
    } else {
      int ii = (int)(i - sum_m);
      int p = ii / CHUNK, j = ii & (CHUNK - 1);
      const float* b = partial + col_off + (size_t)(p * REP) * CHUNK + j;
      float at = 0.0f;
#pragma unroll
      for (int s = 0; s < REP; ++s)
        at += __builtin_nontemporal_load(b + (size_t)s * CHUNK);
      float sv = at + ccat[ii];
      st += (double)sv * sv;
    }
  }
  for (int off = 32; off > 0; off >>= 1) {
    pr += __shfl_down(pr, off);
    du += __shfl_down(du, off);
    st += __shfl_down(st, off);
    cs += __shfl_down(cs, off);
  }
  __shared__ double sred[THREADS / 64][4];
  const int wv = threadIdx.x >> 6;
  if ((threadIdx.x & 63) == 0) {
    sred[wv][0] = pr; sred[wv][1] = du; sred[wv][2] = st; sred[wv][3] = cs;
  }
  __syncthreads();
  if (threadIdx.x == 0) {
    double a0 = 0, a1 = 0, a2 = 0, a3 = 0;
#pragma unroll
    for (int w = 0; w < THREADS / 64; ++w) {
      a0 += sred[w][0]; a1 += sred[w][1]; a2 += sred[w][2]; a3 += sred[w][3];
    }
    bacc[(size_t)blockIdx.x * 4 + 0] = a0;
    bacc[(size_t)blockIdx.x * 4 + 1] = a1;
    bacc[(size_t)blockIdx.x * 4 + 2] = a2;
    bacc[(size_t)blockIdx.x * 4 + 3] = a3;
  }
}

// ---------------------------------------------------------------------------
// finalize (fast path): sum per-block partials, apply weights. 1 block.
// ---------------------------------------------------------------------------
__global__ __launch_bounds__(THREADS) void kkt_finalize_fast(
    const double* __restrict__ bacc, int nblk,
    const int* __restrict__ Bp, const int* __restrict__ mp,
    const int* __restrict__ np_, float* __restrict__ out) {
  double v0 = 0, v1 = 0, v2 = 0, v3 = 0;
  for (int i = threadIdx.x; i < nblk; i += THREADS) {
    v0 += bacc[(size_t)i * 4 + 0];
    v1 += bacc[(size_t)i * 4 + 1];
    v2 += bacc[(size_t)i * 4 + 2];
    v3 += bacc[(size_t)i * 4 + 3];
  }
  for (int off = 32; off > 0; off >>= 1) {
    v0 += __shfl_down(v0, off);
    v1 += __shfl_down(v1, off);
    v2 += __shfl_down(v2, off);
    v3 += __shfl_down(v3, off);
  }
  __shared__ double sred[THREADS / 64][4];
  const int wv = threadIdx.x >> 6;
  if ((threadIdx.x & 63) == 0) {
    sred[wv][0] = v0; sred[wv][1] = v1; sred[wv][2] = v2; sred[wv][3] = v3;
  }
  __syncthreads();
  if (threadIdx.x == 0) {
    double a0 = 0, a1 = 0, a2 = 0, a3 = 0;
#pragma unroll
    for (int w = 0; w < THREADS / 64; ++w) {
      a0 += sred[w][0]; a1 += sred[w][1]; a2 += sred[w][2]; a3 += sred[w][3];
    }
    double m = (double)mp[0];
    double n = (double)np_[0];
    double B = (double)Bp[0];
    out[0] = (float)((0.1 * (a0 + a1) / m + 0.6 * a2 / n + 0.2 * a3 / m) / B);
  }
}

// ---------------------------------------------------------------------------
// Dynamic-REP fallback (proven R3 path) for unexpected ws sizes.
// ---------------------------------------------------------------------------
__global__ void kkt_init(double* __restrict__ acc, float* __restrict__ out) {
  int t = threadIdx.x;
  if (t < 4) acc[t] = 0.0;
  if (t == 0) out[0] = 0.0f;
}

__global__ __launch_bounds__(SCAN_THREADS) void kkt_scan_dyn(
    const int* __restrict__ rows, const int* __restrict__ cols,
    const float* __restrict__ attr,
    const float* __restrict__ x, const float* __restrict__ lam,
    float* __restrict__ partial, int E, int REP) {
  __shared__ float lds[CSZ];
  const int p = blockIdx.x / REP;
  const int r = blockIdx.x % REP;
  const int baseM = p * CM;
  const int baseN = p * CN;
  vfloat4* l4 = (vfloat4*)lds;
  for (int i = threadIdx.x; i < CSZ / 4; i += SCAN_THREADS) l4[i] = (vfloat4)(0.0f);
  __syncthreads();
  long per = (((long)E + REP - 1) / REP + 3) & ~3L;
  long e0 = per * r;  if (e0 > E) e0 = E;
  long e1 = e0 + per; if (e1 > E) e1 = E;
  int  n4 = (int)((e1 - e0) >> 2);
  const vint4*   rows4 = (const vint4*)(rows + e0);
  const vint4*   cols4 = (const vint4*)(cols + e0);
  const vfloat4* attr4 = (const vfloat4*)(attr + e0);
#define EDGE_ACC(RR, CC, AA)                                                 \
  do {                                                                       \
    unsigned mm = (unsigned)((RR) - baseM);                                  \
    if (mm < (unsigned)CM) unsafeAtomicAdd(&lds[mm], (AA) * x[(CC)]);        \
    unsigned nn = (unsigned)((CC) - baseN);                                  \
    if (nn < (unsigned)CN) unsafeAtomicAdd(&lds[CM + nn], (AA) * lam[(RR)]); \
  } while (0)
  for (int i = threadIdx.x; i < n4; i += SCAN_THREADS) {
    vint4 rr = rows4[i]; vint4 cc = cols4[i]; vfloat4 aa = attr4[i];
    EDGE_ACC(rr.x, cc.x, aa.x);
    EDGE_ACC(rr.y, cc.y, aa.y);
    EDGE_ACC(rr.z, cc.z, aa.z);
    EDGE_ACC(rr.w, cc.w, aa.w);
  }
  for (long i = e0 + ((long)n4 << 2) + threadIdx.x; i < e1; i += SCAN_THREADS) {
    int rr = rows[i], cc = cols[i];
    float aa = attr[i];
    EDGE_ACC(rr, cc, aa);
  }
#undef EDGE_ACC
  __syncthreads();
  vfloat4* d4 = (vfloat4*)(partial + (size_t)(p * REP + r) * CSZ);
  for (int i = threadIdx.x; i < CSZ / 4; i += SCAN_THREADS) d4[i] = l4[i];
}

__global__ __launch_bounds__(THREADS) void kkt_loss_dyn(
    const float* __restrict__ partial,
    const float* __restrict__ bcat, const float* __restrict__ ccat,
    const float* __restrict__ lam, double* __restrict__ acc,
    int sum_m, int sum_n, int REP) {
  int idx = blockIdx.x * blockDim.x + threadIdx.x;
  int stride = gridDim.x * blockDim.x;
  double pr = 0.0, du = 0.0, st = 0.0, cs = 0.0;
  for (int i = idx; i < sum_m; i += stride) {
    int p = i / CM, j = i - p * CM;
    const float* base = partial + (size_t)(p * REP) * CSZ + j;
    float ax = 0.0f;
    for (int rr = 0; rr < REP; ++rr) ax += base[(size_t)rr * CSZ];
    float d  = ax - bcat[i];
    float li = lam[i];
    float pp   = d > 0.0f ? d : 0.0f;
    float u    = li < 0.0f ? -li : 0.0f;
    float comp = li * d;
    pr += (double)pp * pp;
    du += (double)u * u;
    cs += (double)comp * comp;
  }
  for (int i = idx; i < sum_n; i += stride) {
    int p = i / CN, j = i - p * CN;
    const float* base = partial + (size_t)(p * REP) * CSZ + CM + j;
    float at = 0.0f;
    for (int rr = 0; rr < REP; ++rr) at += base[(size_t)rr * CSZ];
    float s = at + ccat[i];
    st += (double)s * s;
  }
  for (int off = 32; off > 0; off >>= 1) {
    pr += __shfl_down(pr, off);
    du += __shfl_down(du, off);
    st += __shfl_down(st, off);
    cs += __shfl_down(cs, off);
  }
  if ((threadIdx.x & 63) == 0) {
    unsafeAtomicAdd(&acc[0], pr);
    unsafeAtomicAdd(&acc[1], du);
    unsafeAtomicAdd(&acc[2], st);
    unsafeAtomicAdd(&acc[3], cs);
  }
}

__global__ void kkt_finalize(const double* __restrict__ acc,
                             const int* __restrict__ Bp,
                             const int* __restrict__ mp,
                             const int* __restrict__ np_,
                             float* __restrict__ out) {
  double m = (double)mp[0];
  double n = (double)np_[0];
  double B = (double)Bp[0];
  double total =
      (0.1 * (acc[0] + acc[1]) / m + 0.6 * acc[2] / n + 0.2 * acc[3] / m) / B;
  out[0] = (float)total;
}

extern "C" void kernel_launch(void* const* d_in, const int* in_sizes, int n_in,
                              void* d_out, int out_size, void* d_ws, size_t ws_size,
                              hipStream_t stream) {
  const float* x    = (const float*)d_in[0];
  const float* lam  = (const float*)d_in[1];
  const int*   rows = (const int*)d_in[2];
  const int*   cols = (const int*)d_in[3];
  const float* attr = (const float*)d_in[4];
  const float* bcat = (const float*)d_in[5];
  const float* ccat = (const float*)d_in[6];
  const int*   Bp   = (const int*)d_in[7];
  const int*   mp   = (const int*)d_in[8];
  const int*   np_  = (const int*)d_in[9];

  const int sum_n = in_sizes[0];
  const int sum_m = in_sizes[1];
  const int E     = in_sizes[2];

  char*   ws   = (char*)d_ws;
  double* acc  = (double*)ws;                    // 32 B (fallback)
  double* bacc = (double*)(ws + 256);            // LOSS_BLOCKS*4 doubles
  float*  buf  = (float*)(ws + 256 + LOSS_BLOCKS * 4 * sizeof(double));
  float*  out  = (float*)d_out;

  const int NPr = (sum_m + CHUNK - 1) / CHUNK;
  const int NPc = (sum_n + CHUNK - 1) / CHUNK;
  const int NQ  = NPr + NPc;

  const size_t head = 256 + (size_t)LOSS_BLOCKS * 4 * sizeof(double);
  size_t avail = ws_size > head ? ws_size - head : 0;
  const size_t need_t = (size_t)NQ * REP_T * CHUNK * sizeof(float);

  if (avail >= need_t) {
    // fast path: split row/col scan + atomic-free hierarchical reduction
    kkt_scan2_t<REP_T><<<NQ * REP_T, SCAN_THREADS, 0, stream>>>(
        rows, cols, attr, x, lam, buf, E, NPr);
    kkt_loss2_t<REP_T><<<LOSS_BLOCKS, THREADS, 0, stream>>>(
        buf, bcat, ccat, lam, bacc, sum_m, sum_n, NPr);
    kkt_finalize_fast<<<1, THREADS, 0, stream>>>(bacc, LOSS_BLOCKS, Bp, mp,
                                                 np_, out);
  } else {
    // proven R3-family fallback
    float* fbuf = (float*)(ws + 64);
    const int NPm = (sum_m + CM - 1) / CM;
    const int NPn = (sum_n + CN - 1) / CN;
    const int NP  = NPm > NPn ? NPm : NPn;
    size_t favail = ws_size > 64 ? ws_size - 64 : 0;
    int REP = (int)(favail / ((size_t)NP * CSZ * sizeof(float)));
    if (REP > MAX_REP) REP = MAX_REP;
    if (REP < 1) REP = 1;
    kkt_init<<<1, 64, 0, stream>>>(acc, out);
    kkt_scan_dyn<<<NP * REP, SCAN_THREADS, 0, stream>>>(rows, cols, attr, x,
                                                        lam, fbuf, E, REP);
    int lw = sum_m > sum_n ? sum_m : sum_n;
    int lb = (lw + THREADS - 1) / THREADS;
    if (lb > 1024) lb = 1024;
    kkt_loss_dyn<<<lb, THREADS, 0, stream>>>(fbuf, bcat, ccat, lam, acc,
                                             sum_m, sum_n, REP);
    kkt_finalize<<<1, 1, 0, stream>>>(acc, Bp, mp, np_, out);
  }
}